// Round 5
// baseline (64.720 us; speedup 1.0000x reference)
//
#include <hip/hip_runtime.h>
#include <math.h>

// CTransformer on MI355X, round 5:
//   k_prep     : Wqkv/Wout fp32->bf16 + pad_k/pad_v vectors (LN(0)=ln_b)
//   k_ln_qkv   : FUSED LayerNorm + QKV GEMM. Block = 64 pixels x 768 outputs,
//                512 threads. LN'd activations live in swizzled LDS (no x2bf);
//                W staged per 64-k chunk via global_load_lds w/ pre-swizzled src.
//   k_attn_proj: fused attention + out-proj (XCD-swizzled grid for k/v L2 reuse)

#define NPIX 16384
#define HW   4096
#define CDIM 256

typedef short  bf16x8 __attribute__((ext_vector_type(8)));
typedef float  f32x4  __attribute__((ext_vector_type(4)));
typedef unsigned short u16x8 __attribute__((ext_vector_type(8)));

__device__ inline float bf2f(unsigned short u) {
    unsigned v = ((unsigned)u) << 16;
    return __builtin_bit_cast(float, v);
}
__device__ inline unsigned short f2bf(float f) {   // round-to-nearest-even
    unsigned u = __builtin_bit_cast(unsigned, f);
    u += 0x7FFFu + ((u >> 16) & 1u);
    return (unsigned short)(u >> 16);
}

// ---- prep: weight conversions + pad vectors --------------------------------
__global__ __launch_bounds__(256) void k_prep(const float* __restrict__ Wqkv,
                                              const float* __restrict__ Wout,
                                              const float* __restrict__ bqkv,
                                              const float* __restrict__ lnb,
                                              unsigned short* __restrict__ Wqkvbf,
                                              unsigned short* __restrict__ Woutbf,
                                              float* __restrict__ pads) {
    int bid = blockIdx.x, t = threadIdx.x;
    if (bid < 768) {
        int i = bid * 256 + t;
        Wqkvbf[i] = f2bf(Wqkv[i]);
    } else if (bid < 1024) {
        int i = (bid - 768) * 256 + t;
        Woutbf[i] = f2bf(Wout[i]);
    } else {
        int d = (bid - 1024) * 256 + t;    // 0..511; k rows 256..511, v rows 512..767
        int row = 256 + d;
        const float* wrow = Wqkv + (size_t)row * CDIM;
        float s = bqkv[row];
        for (int c = 0; c < CDIM; ++c) s += lnb[c] * wrow[c];
        pads[d] = s;
    }
}

// ---- FUSED LayerNorm + QKV GEMM --------------------------------------------
// Block: 64 pixels x 768 d, 512 threads (8 waves = 2 pix-halves x 4 d-quarters).
// As[64][256] bf16, XOR-swizzled (chunk ^= pix&7 on 16B granularity).
// Bs[256][64] bf16 per (d-pass, k-chunk), global_load_lds with pre-swizzled src.
__global__ __launch_bounds__(512) void k_ln_qkv(const float* __restrict__ src,
                                                const float* __restrict__ lnw,
                                                const float* __restrict__ lnb,
                                                const unsigned short* __restrict__ Wbf,
                                                const float* __restrict__ bias,
                                                unsigned short* __restrict__ qkvbf) {
    __shared__ unsigned short As[64 * 256];   // 32 KB swizzled [pix][c]
    __shared__ unsigned short Bs[256 * 64];   // 32 KB [d][k] (src-swizzled); reused as Ct
    __shared__ float red[8][65];
    __shared__ float red2[8][65];
    __shared__ float muv[64], rsv[64];

    int t = threadIdx.x;
    int n0 = blockIdx.x * 64;
    int b = n0 >> 12, p0 = n0 & 4095;

    // ---- LN phase: thread (q = t>>6, pix = t&63) handles 32 channels -------
    int q = t >> 6, pix = t & 63;
    const float* sp = src + ((size_t)b * CDIM) * HW + p0 + pix;
    float x[32];
    float sum = 0.f, sq = 0.f;
    #pragma unroll
    for (int i = 0; i < 32; ++i) {
        x[i] = sp[(size_t)(q * 32 + i) * HW];
        sum += x[i]; sq += x[i] * x[i];
    }
    red[q][pix] = sum; red2[q][pix] = sq;
    __syncthreads();
    if (t < 64) {
        float s = 0.f, s2 = 0.f;
        #pragma unroll
        for (int qq = 0; qq < 8; ++qq) { s += red[qq][t]; s2 += red2[qq][t]; }
        float mu = s * (1.f / 256.f);
        float var = fmaxf(s2 * (1.f / 256.f) - mu * mu, 0.f);
        muv[t] = mu; rsv[t] = rsqrtf(var + 1e-5f);
    }
    __syncthreads();
    {
        float mu = muv[pix], rs = rsv[pix];
        #pragma unroll
        for (int c8 = 0; c8 < 4; ++c8) {
            u16x8 o8;
            #pragma unroll
            for (int j = 0; j < 8; ++j) {
                int c = q * 32 + c8 * 8 + j;
                float xn = (x[c8 * 8 + j] - mu) * rs * lnw[c] + lnb[c];
                o8[j] = f2bf(xn);
            }
            int chunk = q * 4 + c8;
            *(u16x8*)((char*)As + (pix * 512 + ((chunk ^ (pix & 7)) * 16))) = o8;
        }
    }
    // As becomes visible to all waves at the first barrier inside the k-loop.

    // ---- GEMM phase ---------------------------------------------------------
    int lane = t & 63, wv = t >> 6;
    int wm = wv >> 2, wn = wv & 3;            // 2 x 4 wave grid, wave = 32pix x 64d
    int lr = lane & 15, lg = lane >> 4;
    int swc = (lane & 7) ^ (lane >> 3);       // pre-swizzled source chunk for staging

    for (int d0 = 0; d0 < 768; d0 += 256) {
        f32x4 acc[2][4] = {};
        for (int k0 = 0; k0 < 256; k0 += 64) {
            __syncthreads();                  // Bs region free; As ready (1st iter)
            #pragma unroll
            for (int it = 0; it < 4; ++it) {
                int rbase = it * 64 + wv * 8;     // wave-uniform, rbase&7 == 0
                const unsigned short* gs =
                    Wbf + (size_t)(d0 + rbase + (lane >> 3)) * 256 + k0 + swc * 8;
                __builtin_amdgcn_global_load_lds(
                    (const __attribute__((address_space(1))) void*)gs,
                    (__attribute__((address_space(3))) void*)(Bs + rbase * 64),
                    16, 0, 0);
            }
            __syncthreads();
            #pragma unroll
            for (int kk = 0; kk < 2; ++kk) {
                int chA = (k0 >> 3) + kk * 4 + lg;   // global k chunk (0..31)
                int chB = kk * 4 + lg;               // Bs-local chunk (0..7)
                bf16x8 a[2], bb[4];
                #pragma unroll
                for (int i = 0; i < 2; ++i) {
                    int r = wm * 32 + i * 16 + lr;
                    a[i] = *(bf16x8*)((char*)As + (r * 512 + ((chA ^ (r & 7)) * 16)));
                }
                #pragma unroll
                for (int j = 0; j < 4; ++j) {
                    int rb = wn * 64 + j * 16 + lr;
                    bb[j] = *(bf16x8*)((char*)Bs + (rb * 128 + ((chB ^ (rb & 7)) * 16)));
                }
                #pragma unroll
                for (int i = 0; i < 2; ++i)
                    #pragma unroll
                    for (int j = 0; j < 4; ++j)
                        acc[i][j] = __builtin_amdgcn_mfma_f32_16x16x32_bf16(
                            a[i], bb[j], acc[i][j], 0, 0, 0);
            }
        }
        // ---- epilogue for this d-pass: two pixel-halves via Ct = Bs region --
        unsigned short* Ct = Bs;                 // [32][264] u16 = 16.9 KB
        #pragma unroll
        for (int h = 0; h < 2; ++h) {
            __syncthreads();                     // Bs reads / previous stores done
            if (wm == h) {
                #pragma unroll
                for (int j = 0; j < 4; ++j) {
                    float bj = bias[d0 + wn * 64 + j * 16 + lr];
                    #pragma unroll
                    for (int i = 0; i < 2; ++i)
                        #pragma unroll
                        for (int r = 0; r < 4; ++r)
                            Ct[(i * 16 + lg * 4 + r) * 264 + wn * 64 + j * 16 + lr] =
                                f2bf(acc[i][j][r] + bj);
                }
            }
            __syncthreads();
            int row = t >> 4, cb = t & 15;       // 32 rows x (16 chunks x 2)
            #pragma unroll
            for (int s = 0; s < 2; ++s) {
                int chunk = cb + 16 * s;
                bf16x8 v = *(bf16x8*)(Ct + row * 264 + chunk * 8);
                *(bf16x8*)(qkvbf + (size_t)(n0 + h * 32 + row) * 768 + d0 + chunk * 8) = v;
            }
        }
    }
}

// ---- global_load_lds staging: 256 rows x 64 k bf16, row stride 256 ---------
__device__ inline void stage64(const unsigned short* __restrict__ g,
                               unsigned short* lds, int t) {
    int lane = t & 63;
    int wv   = t >> 6;
    #pragma unroll
    for (int it = 0; it < 4; ++it) {
        int rbase = wv * 32 + it * 8;                    // wave-uniform
        const unsigned short* src = g + (size_t)(rbase + (lane >> 3)) * 256 + (lane & 7) * 8;
        __builtin_amdgcn_global_load_lds(
            (const __attribute__((address_space(1))) void*)src,
            (__attribute__((address_space(3))) void*)(lds + rbase * 64),
            16, 0, 0);
    }
}

// ---- FUSED attention + out-proj --------------------------------------------
// Block = 64 pixels (one image row) x 256 out channels; 512 threads (8 waves).
// XCD-swizzled grid: each XCD owns 32 consecutive image rows -> k/v halo L2 hits.
__global__ __launch_bounds__(512) void k_attn_proj(const unsigned short* __restrict__ qkvbf,
                                                   const float* __restrict__ pads,
                                                   const unsigned short* __restrict__ Wbf,
                                                   const float* __restrict__ bias,
                                                   const float* __restrict__ src,
                                                   float* __restrict__ out) {
    __shared__ unsigned short Bt[64 * 264];   // attention out [pix][c], pad 264
    __shared__ unsigned short As[256 * 64];   // W tile [ch][k-chunk]
    int t  = threadIdx.x;
    int bid = blockIdx.x;
    int sb  = (bid & 7) * 32 + (bid >> 3);    // 256 = 8 XCDs x 32, bijective
    int n0 = sb * 64;
    int b  = n0 >> 12;
    int p0 = n0 & 4095;

    // ---- phase 1: attention for 64 pixels ----
    {
        int pix = t >> 3, h = t & 7;
        int n = n0 + pix;
        int p = n & 4095, hh0 = p >> 6, ww0 = p & 63;
        const float scale = 0.1767766952966369f;  // 1/sqrt(32)

        float qv[32];
        const unsigned short* qp = qkvbf + (size_t)n * 768 + h * 32;
        #pragma unroll
        for (int c8 = 0; c8 < 4; ++c8) {
            bf16x8 v = *(const bf16x8*)(qp + c8 * 8);
            #pragma unroll
            for (int j = 0; j < 8; ++j) qv[c8 * 8 + j] = bf2f((unsigned short)v[j]) * scale;
        }
        float sc[9];
        #pragma unroll
        for (int t9 = 0; t9 < 9; ++t9) {
            int dy = t9 / 3 - 1, dx = t9 % 3 - 1;
            int hh = hh0 + dy, ww = ww0 + dx;
            bool ok = ((unsigned)hh < 64u) && ((unsigned)ww < 64u);
            float a = 0.f;
            if (ok) {
                const unsigned short* kp = qkvbf + (size_t)(n + dy * 64 + dx) * 768 + 256 + h * 32;
                #pragma unroll
                for (int c8 = 0; c8 < 4; ++c8) {
                    bf16x8 v = *(const bf16x8*)(kp + c8 * 8);
                    #pragma unroll
                    for (int j = 0; j < 8; ++j) a += qv[c8 * 8 + j] * bf2f((unsigned short)v[j]);
                }
            } else {
                const float* pk = pads + h * 32;
                #pragma unroll
                for (int j = 0; j < 32; ++j) a += qv[j] * pk[j];
            }
            sc[t9] = a;
        }
        float m = sc[0];
        #pragma unroll
        for (int t9 = 1; t9 < 9; ++t9) m = fmaxf(m, sc[t9]);
        float s = 0.f;
        #pragma unroll
        for (int t9 = 0; t9 < 9; ++t9) { sc[t9] = __expf(sc[t9] - m); s += sc[t9]; }
        float inv = 1.0f / s;

        float ov[32];
        #pragma unroll
        for (int j = 0; j < 32; ++j) ov[j] = 0.f;
        #pragma unroll
        for (int t9 = 0; t9 < 9; ++t9) {
            int dy = t9 / 3 - 1, dx = t9 % 3 - 1;
            int hh = hh0 + dy, ww = ww0 + dx;
            bool ok = ((unsigned)hh < 64u) && ((unsigned)ww < 64u);
            float w = sc[t9] * inv;
            if (ok) {
                const unsigned short* vp = qkvbf + (size_t)(n + dy * 64 + dx) * 768 + 512 + h * 32;
                #pragma unroll
                for (int c8 = 0; c8 < 4; ++c8) {
                    bf16x8 v = *(const bf16x8*)(vp + c8 * 8);
                    #pragma unroll
                    for (int j = 0; j < 8; ++j) ov[c8 * 8 + j] += w * bf2f((unsigned short)v[j]);
                }
            } else {
                const float* pv = pads + 256 + h * 32;
                #pragma unroll
                for (int j = 0; j < 32; ++j) ov[j] += w * pv[j];
            }
        }
        #pragma unroll
        for (int c8 = 0; c8 < 4; ++c8) {
            u16x8 o8;
            #pragma unroll
            for (int j = 0; j < 8; ++j) o8[j] = f2bf(ov[c8 * 8 + j]);
            *(u16x8*)(Bt + pix * 264 + h * 32 + c8 * 8) = o8;
        }
    }
    __syncthreads();

    // ---- phase 2: GEMM 256ch x 64pix x 256k ----
    int lane = t & 63, wv = t >> 6;          // 8 waves, wave = 32 ch x 64 pix
    int lr = lane & 15, lg = lane >> 4;
    f32x4 acc[2][4] = {};
    for (int k0 = 0; k0 < 256; k0 += 64) {
        if (k0) __syncthreads();
        stage64(Wbf + k0, As, t);            // 256 rows x 64 k
        __syncthreads();
        #pragma unroll
        for (int kk = 0; kk < 2; ++kk) {
            bf16x8 a[2], bb[4];
            #pragma unroll
            for (int i = 0; i < 2; ++i)
                a[i] = *(bf16x8*)(As + (wv * 32 + i * 16 + lr) * 64 + kk * 32 + lg * 8);
            #pragma unroll
            for (int j = 0; j < 4; ++j)
                bb[j] = *(bf16x8*)(Bt + (j * 16 + lr) * 264 + k0 + kk * 32 + lg * 8);
            #pragma unroll
            for (int i = 0; i < 2; ++i)
                #pragma unroll
                for (int j = 0; j < 4; ++j)
                    acc[i][j] = __builtin_amdgcn_mfma_f32_16x16x32_bf16(
                        a[i], bb[j], acc[i][j], 0, 0, 0);
        }
    }
    #pragma unroll
    for (int i = 0; i < 2; ++i) {
        #pragma unroll
        for (int r = 0; r < 4; ++r) {
            int dg = wv * 32 + i * 16 + lg * 4 + r;
            float bd = bias[dg];
            #pragma unroll
            for (int j = 0; j < 4; ++j) {
                int ng = p0 + j * 16 + lr;
                size_t idx = ((size_t)(b * CDIM + dg)) * HW + ng;
                out[idx] = acc[i][j][r] + bd + src[idx];
            }
        }
    }
}

extern "C" void kernel_launch(void* const* d_in, const int* in_sizes, int n_in,
                              void* d_out, int out_size, void* d_ws, size_t ws_size,
                              hipStream_t stream) {
    const float* src  = (const float*)d_in[0];
    const float* lnw  = (const float*)d_in[1];
    const float* lnb  = (const float*)d_in[2];
    const float* Wqkv = (const float*)d_in[3];
    const float* bqkv = (const float*)d_in[4];
    const float* Wout = (const float*)d_in[5];
    const float* bout = (const float*)d_in[6];
    float* out = (float*)d_out;

    unsigned short* qkvbf  = (unsigned short*)d_ws;               // 16384*768
    unsigned short* Wqkvbf = qkvbf + (size_t)NPIX * 768;          // 768*256
    unsigned short* Woutbf = Wqkvbf + 768 * 256;                  // 256*256
    float* pads = (float*)(Woutbf + 256 * 256);                   // 512 floats

    k_prep<<<1026, 256, 0, stream>>>(Wqkv, Wout, bqkv, lnb, Wqkvbf, Woutbf, pads);
    k_ln_qkv<<<NPIX / 64, 512, 0, stream>>>(src, lnw, lnb, Wqkvbf, bqkv, qkvbf);
    k_attn_proj<<<NPIX / 64, 512, 0, stream>>>(qkvbf, pads, Woutbf, bout, src, out);
}

// Round 6
// 55.281 us; speedup vs baseline: 1.1707x; 1.1707x over previous
//
#include <hip/hip_runtime.h>
#include <math.h>

// CTransformer on MI355X, round 6: 32-pixel blocks (2 independent blocks/CU for
// drain overlap), both-sides swizzled W staging everywhere, XCD-swizzled grids.
//   k_prep     : Wqkv/Wout fp32->bf16 + pad_k/pad_v vectors (LN(0)=ln_b)
//   k_ln_qkv   : fused LayerNorm + QKV GEMM, block = 32 pixels x 768 outputs
//   k_attn_proj: fused attention + out-proj, block = 32 pixels x 256 channels

#define NPIX 16384
#define HW   4096
#define CDIM 256

typedef short  bf16x8 __attribute__((ext_vector_type(8)));
typedef float  f32x4  __attribute__((ext_vector_type(4)));
typedef unsigned short u16x8 __attribute__((ext_vector_type(8)));

__device__ inline float bf2f(unsigned short u) {
    unsigned v = ((unsigned)u) << 16;
    return __builtin_bit_cast(float, v);
}
__device__ inline unsigned short f2bf(float f) {   // round-to-nearest-even
    unsigned u = __builtin_bit_cast(unsigned, f);
    u += 0x7FFFu + ((u >> 16) & 1u);
    return (unsigned short)(u >> 16);
}

// ---- prep: weight conversions + pad vectors --------------------------------
__global__ __launch_bounds__(256) void k_prep(const float* __restrict__ Wqkv,
                                              const float* __restrict__ Wout,
                                              const float* __restrict__ bqkv,
                                              const float* __restrict__ lnb,
                                              unsigned short* __restrict__ Wqkvbf,
                                              unsigned short* __restrict__ Woutbf,
                                              float* __restrict__ pads) {
    int bid = blockIdx.x, t = threadIdx.x;
    if (bid < 768) {
        int i = bid * 256 + t;
        Wqkvbf[i] = f2bf(Wqkv[i]);
    } else if (bid < 1024) {
        int i = (bid - 768) * 256 + t;
        Woutbf[i] = f2bf(Wout[i]);
    } else {
        int d = (bid - 1024) * 256 + t;    // 0..511; k rows 256..511, v rows 512..767
        int row = 256 + d;
        const float* wrow = Wqkv + (size_t)row * CDIM;
        float s = bqkv[row];
        for (int c = 0; c < CDIM; ++c) s += lnb[c] * wrow[c];
        pads[d] = s;
    }
}

// Stage 256 rows x 64 k bf16 of W into LDS, linear dest + pre-swizzled source
// (rule #21: slot s of row r holds source chunk s ^ (r&7)).
__device__ inline void stageW(const unsigned short* __restrict__ g,
                              unsigned short* lds, int t) {
    int lane = t & 63;
    int wv   = t >> 6;                       // 4 waves
    int swc  = (lane & 7) ^ ((lane >> 3) & 7);
    #pragma unroll
    for (int it = 0; it < 8; ++it) {
        int rbase = it * 32 + wv * 8;        // wave-uniform, multiple of 8
        const unsigned short* src = g + (size_t)(rbase + (lane >> 3)) * 256 + swc * 8;
        __builtin_amdgcn_global_load_lds(
            (const __attribute__((address_space(1))) void*)src,
            (__attribute__((address_space(3))) void*)(lds + rbase * 64),
            16, 0, 0);
    }
}

// ---- FUSED LayerNorm + QKV GEMM --------------------------------------------
// Block: 32 pixels x 768 d, 256 threads (4 waves). Grid 512, XCD-swizzled.
// As[32][256] bf16 swizzled (chunk ^= pix&7); Bs[256][64] W (src-swizzled);
// Bs reused as Ct[32][264] for the transpose epilogue.
__global__ __launch_bounds__(256) void k_ln_qkv(const float* __restrict__ src,
                                                const float* __restrict__ lnw,
                                                const float* __restrict__ lnb,
                                                const unsigned short* __restrict__ Wbf,
                                                const float* __restrict__ bias,
                                                unsigned short* __restrict__ qkvbf) {
    __shared__ unsigned short As[32 * 256];   // 16 KB
    __shared__ unsigned short Bs[256 * 64];   // 32 KB
    __shared__ float red[8][33];
    __shared__ float red2[8][33];
    __shared__ float muv[32], rsv[32];

    int t = threadIdx.x;
    int bid = blockIdx.x;
    int sb = (bid & 7) * 64 + (bid >> 3);     // 512 = 8 XCDs x 64, bijective
    int n0 = sb * 32;
    int b = n0 >> 12, p0 = n0 & 4095;

    // ---- LN phase: pix = t&31, q = t>>5 handles channels q*32..q*32+31 -----
    int pix = t & 31, q = t >> 5;
    const float* sp = src + ((size_t)b * CDIM) * HW + p0 + pix;
    float x[32];
    float sum = 0.f, sq = 0.f;
    #pragma unroll
    for (int i = 0; i < 32; ++i) {
        x[i] = sp[(size_t)(q * 32 + i) * HW];
        sum += x[i]; sq += x[i] * x[i];
    }
    red[q][pix] = sum; red2[q][pix] = sq;
    __syncthreads();
    if (t < 32) {
        float s = 0.f, s2 = 0.f;
        #pragma unroll
        for (int qq = 0; qq < 8; ++qq) { s += red[qq][t]; s2 += red2[qq][t]; }
        float mu = s * (1.f / 256.f);
        float var = fmaxf(s2 * (1.f / 256.f) - mu * mu, 0.f);
        muv[t] = mu; rsv[t] = rsqrtf(var + 1e-5f);
    }
    __syncthreads();
    {
        float mu = muv[pix], rs = rsv[pix];
        #pragma unroll
        for (int c8 = 0; c8 < 4; ++c8) {
            u16x8 o8;
            #pragma unroll
            for (int j = 0; j < 8; ++j) {
                int c = q * 32 + c8 * 8 + j;
                float xn = (x[c8 * 8 + j] - mu) * rs * lnw[c] + lnb[c];
                o8[j] = f2bf(xn);
            }
            int chunk = q * 4 + c8;           // 0..31
            *(u16x8*)((char*)As + (pix * 512 + (((chunk & 7) ^ (pix & 7)) | (chunk & 24)) * 16)) = o8;
        }
    }
    // As visible to all waves at the first loop-top barrier.

    // ---- GEMM phase: wave wv owns d-range wv*64 within each 256-d pass ------
    int lane = t & 63, wv = t >> 6;
    int lr = lane & 15, lg = lane >> 4;

    for (int d0 = 0; d0 < 768; d0 += 256) {
        f32x4 acc[2][4] = {};
        for (int k0 = 0; k0 < 256; k0 += 64) {
            __syncthreads();                  // As ready / Bs free
            stageW(Wbf + (size_t)d0 * 256 + k0, Bs, t);
            __syncthreads();
            #pragma unroll
            for (int kk = 0; kk < 2; ++kk) {
                int chA = (k0 >> 3) + kk * 4 + lg;   // global k chunk 0..31
                int chB = kk * 4 + lg;               // Bs-local chunk 0..7
                bf16x8 a[2], bb[4];
                #pragma unroll
                for (int i = 0; i < 2; ++i) {
                    int r = i * 16 + lr;
                    int sl = ((chA & 7) ^ (r & 7)) | (chA & 24);
                    a[i] = *(bf16x8*)((char*)As + (r * 512 + sl * 16));
                }
                #pragma unroll
                for (int j = 0; j < 4; ++j) {
                    int rb = wv * 64 + j * 16 + lr;
                    bb[j] = *(bf16x8*)((char*)Bs + (rb * 128 + ((chB ^ (rb & 7)) * 16)));
                }
                #pragma unroll
                for (int i = 0; i < 2; ++i)
                    #pragma unroll
                    for (int j = 0; j < 4; ++j)
                        acc[i][j] = __builtin_amdgcn_mfma_f32_16x16x32_bf16(
                            a[i], bb[j], acc[i][j], 0, 0, 0);
            }
        }
        // ---- epilogue: acc -> Ct[32][264] (+bias) -> coalesced global ------
        unsigned short* Ct = Bs;
        __syncthreads();                      // Bs reads done
        #pragma unroll
        for (int j = 0; j < 4; ++j) {
            float bj = bias[d0 + wv * 64 + j * 16 + lr];
            #pragma unroll
            for (int i = 0; i < 2; ++i)
                #pragma unroll
                for (int r = 0; r < 4; ++r)
                    Ct[(i * 16 + lg * 4 + r) * 264 + wv * 64 + j * 16 + lr] =
                        f2bf(acc[i][j][r] + bj);
        }
        __syncthreads();
        int row = t >> 3, cb = t & 7;         // 32 rows x 8 lanes
        #pragma unroll
        for (int s = 0; s < 4; ++s) {
            int chunk = cb + 8 * s;           // 0..31
            bf16x8 v = *(bf16x8*)(Ct + row * 264 + chunk * 8);
            *(bf16x8*)(qkvbf + (size_t)(n0 + row) * 768 + d0 + chunk * 8) = v;
        }
    }
}

// ---- FUSED attention + out-proj --------------------------------------------
// Block = 32 pixels x 256 out channels; 256 threads (4 waves). Grid 512,
// XCD-swizzled so each XCD owns contiguous image rows (k/v halo L2 reuse).
__global__ __launch_bounds__(256) void k_attn_proj(const unsigned short* __restrict__ qkvbf,
                                                   const float* __restrict__ pads,
                                                   const unsigned short* __restrict__ Wbf,
                                                   const float* __restrict__ bias,
                                                   const float* __restrict__ src,
                                                   float* __restrict__ out) {
    __shared__ unsigned short Bt[32 * 264];   // attention out [pix][c]  (16.9 KB)
    __shared__ unsigned short As[256 * 64];   // W tile [ch][k], src-swizzled (32 KB)
    int t  = threadIdx.x;
    int bid = blockIdx.x;
    int sb  = (bid & 7) * 64 + (bid >> 3);    // 512 = 8 XCDs x 64, bijective
    int n0 = sb * 32;
    int b  = n0 >> 12;
    int p0 = n0 & 4095;

    // ---- phase 1: attention, thread = (pixel, head) ----
    {
        int pix = t >> 3, h = t & 7;
        int n = n0 + pix;
        int p = n & 4095, hh0 = p >> 6, ww0 = p & 63;
        const float scale = 0.1767766952966369f;  // 1/sqrt(32)

        float qv[32];
        const unsigned short* qp = qkvbf + (size_t)n * 768 + h * 32;
        #pragma unroll
        for (int c8 = 0; c8 < 4; ++c8) {
            bf16x8 v = *(const bf16x8*)(qp + c8 * 8);
            #pragma unroll
            for (int j = 0; j < 8; ++j) qv[c8 * 8 + j] = bf2f((unsigned short)v[j]) * scale;
        }
        float sc[9];
        #pragma unroll
        for (int t9 = 0; t9 < 9; ++t9) {
            int dy = t9 / 3 - 1, dx = t9 % 3 - 1;
            int hh = hh0 + dy, ww = ww0 + dx;
            bool ok = ((unsigned)hh < 64u) && ((unsigned)ww < 64u);
            float a = 0.f;
            if (ok) {
                const unsigned short* kp = qkvbf + (size_t)(n + dy * 64 + dx) * 768 + 256 + h * 32;
                #pragma unroll
                for (int c8 = 0; c8 < 4; ++c8) {
                    bf16x8 v = *(const bf16x8*)(kp + c8 * 8);
                    #pragma unroll
                    for (int j = 0; j < 8; ++j) a += qv[c8 * 8 + j] * bf2f((unsigned short)v[j]);
                }
            } else {
                const float* pk = pads + h * 32;
                #pragma unroll
                for (int j = 0; j < 32; ++j) a += qv[j] * pk[j];
            }
            sc[t9] = a;
        }
        float m = sc[0];
        #pragma unroll
        for (int t9 = 1; t9 < 9; ++t9) m = fmaxf(m, sc[t9]);
        float s = 0.f;
        #pragma unroll
        for (int t9 = 0; t9 < 9; ++t9) { sc[t9] = __expf(sc[t9] - m); s += sc[t9]; }
        float inv = 1.0f / s;

        float ov[32];
        #pragma unroll
        for (int j = 0; j < 32; ++j) ov[j] = 0.f;
        #pragma unroll
        for (int t9 = 0; t9 < 9; ++t9) {
            int dy = t9 / 3 - 1, dx = t9 % 3 - 1;
            int hh = hh0 + dy, ww = ww0 + dx;
            bool ok = ((unsigned)hh < 64u) && ((unsigned)ww < 64u);
            float w = sc[t9] * inv;
            if (ok) {
                const unsigned short* vp = qkvbf + (size_t)(n + dy * 64 + dx) * 768 + 512 + h * 32;
                #pragma unroll
                for (int c8 = 0; c8 < 4; ++c8) {
                    bf16x8 v = *(const bf16x8*)(vp + c8 * 8);
                    #pragma unroll
                    for (int j = 0; j < 8; ++j) ov[c8 * 8 + j] += w * bf2f((unsigned short)v[j]);
                }
            } else {
                const float* pv = pads + 256 + h * 32;
                #pragma unroll
                for (int j = 0; j < 32; ++j) ov[j] += w * pv[j];
            }
        }
        #pragma unroll
        for (int c8 = 0; c8 < 4; ++c8) {
            u16x8 o8;
            #pragma unroll
            for (int j = 0; j < 8; ++j) o8[j] = f2bf(ov[c8 * 8 + j]);
            *(u16x8*)(Bt + pix * 264 + h * 32 + c8 * 8) = o8;
        }
    }
    __syncthreads();

    // ---- phase 2: GEMM 256ch x 32pix x 256k; wave = 64 ch ----
    int lane = t & 63, wv = t >> 6;
    int lr = lane & 15, lg = lane >> 4;
    f32x4 acc[4][2] = {};
    for (int k0 = 0; k0 < 256; k0 += 64) {
        if (k0) __syncthreads();
        stageW(Wbf + k0, As, t);
        __syncthreads();
        #pragma unroll
        for (int kk = 0; kk < 2; ++kk) {
            bf16x8 a[4], bb[2];
            #pragma unroll
            for (int i = 0; i < 4; ++i) {
                int r = wv * 64 + i * 16 + lr;
                int sl = (kk * 4 + lg) ^ (r & 7);
                a[i] = *(bf16x8*)((char*)As + (r * 128 + sl * 16));
            }
            #pragma unroll
            for (int j = 0; j < 2; ++j)
                bb[j] = *(bf16x8*)(Bt + (j * 16 + lr) * 264 + k0 + kk * 32 + lg * 8);
            #pragma unroll
            for (int i = 0; i < 4; ++i)
                #pragma unroll
                for (int j = 0; j < 2; ++j)
                    acc[i][j] = __builtin_amdgcn_mfma_f32_16x16x32_bf16(
                        a[i], bb[j], acc[i][j], 0, 0, 0);
        }
    }
    #pragma unroll
    for (int i = 0; i < 4; ++i) {
        #pragma unroll
        for (int r = 0; r < 4; ++r) {
            int dg = wv * 64 + i * 16 + lg * 4 + r;
            float bd = bias[dg];
            #pragma unroll
            for (int j = 0; j < 2; ++j) {
                int ng = p0 + j * 16 + lr;
                size_t idx = ((size_t)(b * CDIM + dg)) * HW + ng;
                out[idx] = acc[i][j][r] + bd + src[idx];
            }
        }
    }
}

extern "C" void kernel_launch(void* const* d_in, const int* in_sizes, int n_in,
                              void* d_out, int out_size, void* d_ws, size_t ws_size,
                              hipStream_t stream) {
    const float* src  = (const float*)d_in[0];
    const float* lnw  = (const float*)d_in[1];
    const float* lnb  = (const float*)d_in[2];
    const float* Wqkv = (const float*)d_in[3];
    const float* bqkv = (const float*)d_in[4];
    const float* Wout = (const float*)d_in[5];
    const float* bout = (const float*)d_in[6];
    float* out = (float*)d_out;

    unsigned short* qkvbf  = (unsigned short*)d_ws;               // 16384*768
    unsigned short* Wqkvbf = qkvbf + (size_t)NPIX * 768;          // 768*256
    unsigned short* Woutbf = Wqkvbf + 768 * 256;                  // 256*256
    float* pads = (float*)(Woutbf + 256 * 256);                   // 512 floats

    k_prep<<<1026, 256, 0, stream>>>(Wqkv, Wout, bqkv, lnb, Wqkvbf, Woutbf, pads);
    k_ln_qkv<<<512, 256, 0, stream>>>(src, lnw, lnb, Wqkvbf, bqkv, qkvbf);
    k_attn_proj<<<512, 256, 0, stream>>>(qkvbf, pads, Woutbf, bout, src, out);
}